// Round 1
// baseline (696.559 us; speedup 1.0000x reference)
//
#include <hip/hip_runtime.h>

#define BATCH 4
#define DIM   1536
#define SEQ   4096
#define NST   16
#define NCH   32      // chunks per sequence
#define CLEN  128     // chunk length: NCH*CLEN == SEQ
#define NCHAN (BATCH*DIM)

// softplus matching jax.nn.softplus = log1p(exp(z)), overflow-safe
__device__ __forceinline__ float softplus_f(float z) {
    return (z > 20.f) ? z : __logf(1.f + __expf(z));
}

// ---------------- Phase A: per-(channel,chunk) summaries ----------------
// S_n = sum_t (prod_{t'>t} a_{t'}) b_t  (local recurrence, x_in = 0)
// sumdt = sum_t dt_t   (chunk decay = exp(A_n * sumdt))
__global__ __launch_bounds__(256) void ssm_phaseA(
    const float* __restrict__ u, const float* __restrict__ delta,
    const float* __restrict__ Bm, const float* __restrict__ A,
    const float* __restrict__ dbias,
    float* __restrict__ sumdt_out, float* __restrict__ S_out)
{
    __shared__ float ldsB[CLEN * NST];
    const int tid = threadIdx.x;
    const int ch  = blockIdx.x * 256 + tid;       // channel = b*DIM + d
    const int d   = ch % DIM;
    const int bb  = (blockIdx.x * 256) / DIM;     // uniform per block (1536%256==0)
    const int k   = blockIdx.y;
    const int s0  = k * CLEN;

    // stage B chunk: lds[i*16+n] = B[bb, n, s0+i]  (n-fast -> conflict-free LDS writes)
    for (int idx = tid; idx < CLEN * NST; idx += 256) {
        const int i = idx >> 4, n = idx & 15;
        ldsB[idx] = Bm[((size_t)(bb * NST + n)) * SEQ + s0 + i];
    }
    __syncthreads();

    float Arow[NST];
    const float* Ap = A + d * NST;
#pragma unroll
    for (int n = 0; n < NST; n++) Arow[n] = Ap[n];
    const float bias = dbias[d];

    const float* up = u     + (size_t)ch * SEQ + s0;
    const float* dp = delta + (size_t)ch * SEQ + s0;

    float S[NST];
#pragma unroll
    for (int n = 0; n < NST; n++) S[n] = 0.f;
    float sumdt = 0.f;

    for (int i = 0; i < CLEN; i += 4) {
        const float4 uv = *(const float4*)(up + i);
        const float4 dv = *(const float4*)(dp + i);
        const float uu[4] = {uv.x, uv.y, uv.z, uv.w};
        const float dd[4] = {dv.x, dv.y, dv.z, dv.w};
#pragma unroll
        for (int j = 0; j < 4; j++) {
            const float dt  = softplus_f(dd[j] + bias);
            const float dtu = dt * uu[j];
            sumdt += dt;
            const float* bi = &ldsB[(i + j) * NST];
#pragma unroll
            for (int n = 0; n < NST; n++) {
                const float a = __expf(dt * Arow[n]);
                S[n] = a * S[n] + dtu * bi[n];
            }
        }
    }

    const size_t base = ((size_t)ch * NCH + k) * NST;
#pragma unroll
    for (int n = 0; n < NST; n++) S_out[base + n] = S[n];
    sumdt_out[(size_t)ch * NCH + k] = sumdt;
}

// ---------------- Phase B: scan chunk summaries -> chunk entry states ----
// In-place: S[ch][k][n] becomes x0 (state entering chunk k).
__global__ __launch_bounds__(256) void ssm_phaseB(
    const float* __restrict__ A, const float* __restrict__ sumdt,
    float* __restrict__ S)
{
    const int t  = blockIdx.x * 256 + threadIdx.x;
    const int n  = t & 15;
    const int ch = t >> 4;
    if (ch >= NCHAN) return;
    const int d = ch % DIM;
    const float An = A[d * NST + n];
    float x = 0.f;
    for (int k = 0; k < NCH; k++) {
        const size_t idx = ((size_t)ch * NCH + k) * NST + n;
        const float s_old = S[idx];
        S[idx] = x;                                  // x0 for chunk k
        const float P = __expf(An * sumdt[(size_t)ch * NCH + k]);
        x = P * x + s_old;                           // state after chunk k
    }
}

// ---------------- Phase C: replay chunk from x0, emit y ------------------
__global__ __launch_bounds__(256) void ssm_phaseC(
    const float* __restrict__ u, const float* __restrict__ delta,
    const float* __restrict__ Bm, const float* __restrict__ Cm,
    const float* __restrict__ A, const float* __restrict__ Dv,
    const float* __restrict__ dbias, const float* __restrict__ x0,
    float* __restrict__ y)
{
    __shared__ float ldsB[CLEN * NST];
    __shared__ float ldsC[CLEN * NST];
    const int tid = threadIdx.x;
    const int ch  = blockIdx.x * 256 + tid;
    const int d   = ch % DIM;
    const int bb  = (blockIdx.x * 256) / DIM;
    const int k   = blockIdx.y;
    const int s0  = k * CLEN;

    for (int idx = tid; idx < CLEN * NST; idx += 256) {
        const int i = idx >> 4, n = idx & 15;
        const size_t g = ((size_t)(bb * NST + n)) * SEQ + s0 + i;
        ldsB[idx] = Bm[g];
        ldsC[idx] = Cm[g];
    }
    __syncthreads();

    float Arow[NST];
    const float* Ap = A + d * NST;
#pragma unroll
    for (int n = 0; n < NST; n++) Arow[n] = Ap[n];
    const float bias = dbias[d];
    const float Dval = Dv[d];

    float x[NST];
    const size_t xbase = ((size_t)ch * NCH + k) * NST;
#pragma unroll
    for (int n = 0; n < NST; n++) x[n] = x0[xbase + n];

    const float* up = u     + (size_t)ch * SEQ + s0;
    const float* dp = delta + (size_t)ch * SEQ + s0;
    float*       yp = y     + (size_t)ch * SEQ + s0;

    for (int i = 0; i < CLEN; i += 4) {
        const float4 uv = *(const float4*)(up + i);
        const float4 dv = *(const float4*)(dp + i);
        const float uu[4] = {uv.x, uv.y, uv.z, uv.w};
        const float dd[4] = {dv.x, dv.y, dv.z, dv.w};
        float yy[4];
#pragma unroll
        for (int j = 0; j < 4; j++) {
            const float dt  = softplus_f(dd[j] + bias);
            const float dtu = dt * uu[j];
            const float* bi = &ldsB[(i + j) * NST];
            const float* ci = &ldsC[(i + j) * NST];
            float acc = Dval * uu[j];
#pragma unroll
            for (int n = 0; n < NST; n++) {
                const float a = __expf(dt * Arow[n]);
                x[n] = a * x[n] + dtu * bi[n];
                acc += x[n] * ci[n];
            }
            yy[j] = acc;
        }
        *(float4*)(yp + i) = make_float4(yy[0], yy[1], yy[2], yy[3]);
    }
}

extern "C" void kernel_launch(void* const* d_in, const int* in_sizes, int n_in,
                              void* d_out, int out_size, void* d_ws, size_t ws_size,
                              hipStream_t stream)
{
    const float* u     = (const float*)d_in[0];
    const float* delta = (const float*)d_in[1];
    const float* Bm    = (const float*)d_in[2];
    const float* Cm    = (const float*)d_in[3];
    const float* A     = (const float*)d_in[4];
    const float* Dv    = (const float*)d_in[5];
    const float* dbias = (const float*)d_in[6];
    float* y = (float*)d_out;

    // workspace: sumdt [NCHAN*NCH] then S/x0 [NCHAN*NCH*NST]  (~13.4 MB total)
    float* sumdt = (float*)d_ws;
    float* S     = sumdt + (size_t)NCHAN * NCH;

    const dim3 grid(NCHAN / 256, NCH);
    ssm_phaseA<<<grid, 256, 0, stream>>>(u, delta, Bm, A, dbias, sumdt, S);
    ssm_phaseB<<<(NCHAN * NST) / 256, 256, 0, stream>>>(A, sumdt, S);
    ssm_phaseC<<<grid, 256, 0, stream>>>(u, delta, Bm, Cm, A, Dv, dbias, S, y);
}

// Round 2
// 495.547 us; speedup vs baseline: 1.4056x; 1.4056x over previous
//
#include <hip/hip_runtime.h>

#define BATCH 4
#define DIM   1536
#define SEQ   4096
#define NST   16
#define NCH   32      // chunks per sequence
#define CLEN  128     // chunk length: NCH*CLEN == SEQ
#define NCHAN (BATCH*DIM)
#define T     16      // subtile steps staged in LDS
#define LSTR  17      // padded LDS row stride (floats) -> <=2-way bank aliasing (free)

#define LOG2E 1.4426950408889634f

// softplus matching jax.nn.softplus = log1p(exp(z)), overflow-safe
__device__ __forceinline__ float softplus_f(float z) {
    return (z > 20.f) ? z : __logf(1.f + __expf(z));
}

__device__ __forceinline__ float exp2_hw(float z) {
    return __builtin_amdgcn_exp2f(z);
}

// ---------------- Phase A: per-(channel,chunk) summaries ----------------
// S_n = sum_t (prod_{t'>t} a_{t'}) b_t  (local recurrence, x_in = 0)
// sumdt = sum_t dt_t   (chunk decay = exp2(A2_n * sumdt), A2 = A/ln2)
// S layout: [k][ch][n]  (coalesced for phases B and C)
__global__ __launch_bounds__(256) void ssm_phaseA(
    const float* __restrict__ u, const float* __restrict__ delta,
    const float* __restrict__ Bm, const float* __restrict__ A,
    const float* __restrict__ dbias,
    float* __restrict__ sumdt_out, float* __restrict__ S_out)
{
    __shared__ float lu[256 * LSTR];
    __shared__ float ld[256 * LSTR];
    __shared__ float lB[T * NST];

    const int tid = threadIdx.x;
    const int ch  = blockIdx.x * 256 + tid;       // channel = b*DIM + d
    const int d   = ch % DIM;
    const int bb  = (blockIdx.x * 256) / DIM;     // uniform per block (1536%256==0)
    const int k   = blockIdx.y;
    const int s0  = k * CLEN;

    float Arow2[NST];
    const float* Ap = A + d * NST;
#pragma unroll
    for (int n = 0; n < NST; n++) Arow2[n] = Ap[n] * LOG2E;
    const float bias = dbias[d];

    const size_t gbase = (size_t)(blockIdx.x * 256) * SEQ + s0;  // block's channel0 base

    float S[NST];
#pragma unroll
    for (int n = 0; n < NST; n++) S[n] = 0.f;
    float sumdt = 0.f;

    for (int ss = 0; ss < CLEN; ss += T) {
        __syncthreads();  // previous tile fully consumed before overwrite
        // stage u/delta tile [256 ch x T steps], lane-contiguous float4 global loads
#pragma unroll
        for (int q = 0; q < 4; q++) {
            const int idx = tid + 256 * q;        // 0..1023
            const int co  = idx >> 2;             // channel offset 0..255
            const int i4  = (idx & 3) << 2;       // step offset 0,4,8,12
            const float4 uv = *(const float4*)(u     + gbase + (size_t)co * SEQ + ss + i4);
            const float4 dv = *(const float4*)(delta + gbase + (size_t)co * SEQ + ss + i4);
            float* lup = &lu[co * LSTR + i4];
            float* ldp = &ld[co * LSTR + i4];
            lup[0] = uv.x; lup[1] = uv.y; lup[2] = uv.z; lup[3] = uv.w;
            ldp[0] = dv.x; ldp[1] = dv.y; ldp[2] = dv.z; ldp[3] = dv.w;
        }
        // stage B tile [T x NST], broadcast-read layout
        {
            const int n = tid >> 4, i = tid & 15;
            lB[i * NST + n] = Bm[((size_t)(bb * NST + n)) * SEQ + s0 + ss + i];
        }
        __syncthreads();

        const float* lur = &lu[tid * LSTR];
        const float* ldr = &ld[tid * LSTR];
#pragma unroll
        for (int i = 0; i < T; i++) {
            const float uu  = lur[i];
            const float dt  = softplus_f(ldr[i] + bias);
            const float dtu = dt * uu;
            sumdt += dt;
            const float* bi = &lB[i * NST];
#pragma unroll
            for (int n = 0; n < NST; n++) {
                const float a = exp2_hw(dt * Arow2[n]);
                S[n] = fmaf(a, S[n], dtu * bi[n]);
            }
        }
    }

    const size_t base = ((size_t)k * NCHAN + ch) * NST;   // [k][ch][n]
#pragma unroll
    for (int n = 0; n < NST; n += 4)
        *(float4*)(S_out + base + n) = make_float4(S[n], S[n+1], S[n+2], S[n+3]);
    sumdt_out[(size_t)k * NCHAN + ch] = sumdt;
}

// ---------------- Phase B: scan chunk summaries -> chunk entry states ----
// In-place on S[k][ch][n]: becomes x0 (state entering chunk k).
__global__ __launch_bounds__(256) void ssm_phaseB(
    const float* __restrict__ A, const float* __restrict__ sumdt,
    float* __restrict__ S)
{
    const int t  = blockIdx.x * 256 + threadIdx.x;
    const int n  = t & 15;
    const int ch = t >> 4;
    if (ch >= NCHAN) return;
    const int d = ch % DIM;
    const float An2 = A[d * NST + n] * LOG2E;
    float x = 0.f;
    for (int k = 0; k < NCH; k++) {
        const size_t idx = ((size_t)k * NCHAN + ch) * NST + n;
        const float s_old = S[idx];
        S[idx] = x;                                  // x0 for chunk k
        const float P = exp2_hw(An2 * sumdt[(size_t)k * NCHAN + ch]);
        x = fmaf(P, x, s_old);                       // state after chunk k
    }
}

// ---------------- Phase C: replay chunk from x0, emit y ------------------
__global__ __launch_bounds__(256) void ssm_phaseC(
    const float* __restrict__ u, const float* __restrict__ delta,
    const float* __restrict__ Bm, const float* __restrict__ Cm,
    const float* __restrict__ A, const float* __restrict__ Dv,
    const float* __restrict__ dbias, const float* __restrict__ x0,
    float* __restrict__ y)
{
    __shared__ float lu[256 * LSTR];
    __shared__ float ld[256 * LSTR];
    __shared__ float ly[256 * LSTR];
    __shared__ float lB[T * NST];
    __shared__ float lC[T * NST];

    const int tid = threadIdx.x;
    const int ch  = blockIdx.x * 256 + tid;
    const int d   = ch % DIM;
    const int bb  = (blockIdx.x * 256) / DIM;
    const int k   = blockIdx.y;
    const int s0  = k * CLEN;

    float Arow2[NST];
    const float* Ap = A + d * NST;
#pragma unroll
    for (int n = 0; n < NST; n++) Arow2[n] = Ap[n] * LOG2E;
    const float bias = dbias[d];
    const float Dval = Dv[d];

    float x[NST];
    const size_t xbase = ((size_t)k * NCHAN + ch) * NST;  // [k][ch][n]
#pragma unroll
    for (int n = 0; n < NST; n += 4) {
        const float4 xv = *(const float4*)(x0 + xbase + n);
        x[n] = xv.x; x[n+1] = xv.y; x[n+2] = xv.z; x[n+3] = xv.w;
    }

    const size_t gbase = (size_t)(blockIdx.x * 256) * SEQ + s0;

    for (int ss = 0; ss < CLEN; ss += T) {
        __syncthreads();  // prev tile consumed (incl. ly writeout) before restage
#pragma unroll
        for (int q = 0; q < 4; q++) {
            const int idx = tid + 256 * q;
            const int co  = idx >> 2;
            const int i4  = (idx & 3) << 2;
            const float4 uv = *(const float4*)(u     + gbase + (size_t)co * SEQ + ss + i4);
            const float4 dv = *(const float4*)(delta + gbase + (size_t)co * SEQ + ss + i4);
            float* lup = &lu[co * LSTR + i4];
            float* ldp = &ld[co * LSTR + i4];
            lup[0] = uv.x; lup[1] = uv.y; lup[2] = uv.z; lup[3] = uv.w;
            ldp[0] = dv.x; ldp[1] = dv.y; ldp[2] = dv.z; ldp[3] = dv.w;
        }
        {
            const int n = tid >> 4, i = tid & 15;
            const size_t g = ((size_t)(bb * NST + n)) * SEQ + s0 + ss + i;
            lB[i * NST + n] = Bm[g];
            lC[i * NST + n] = Cm[g];
        }
        __syncthreads();

        const float* lur = &lu[tid * LSTR];
        const float* ldr = &ld[tid * LSTR];
        float*       lyw = &ly[tid * LSTR];
#pragma unroll
        for (int i = 0; i < T; i++) {
            const float uu  = lur[i];
            const float dt  = softplus_f(ldr[i] + bias);
            const float dtu = dt * uu;
            const float* bi = &lB[i * NST];
            const float* ci = &lC[i * NST];
            float acc = Dval * uu;
#pragma unroll
            for (int n = 0; n < NST; n++) {
                const float a = exp2_hw(dt * Arow2[n]);
                x[n] = fmaf(a, x[n], dtu * bi[n]);
                acc  = fmaf(x[n], ci[n], acc);
            }
            lyw[i] = acc;
        }
        __syncthreads();  // ly complete before coalesced writeout
#pragma unroll
        for (int q = 0; q < 4; q++) {
            const int idx = tid + 256 * q;
            const int co  = idx >> 2;
            const int i4  = (idx & 3) << 2;
            const float* lyr = &ly[co * LSTR + i4];
            *(float4*)(y + gbase + (size_t)co * SEQ + ss + i4) =
                make_float4(lyr[0], lyr[1], lyr[2], lyr[3]);
        }
    }
}

extern "C" void kernel_launch(void* const* d_in, const int* in_sizes, int n_in,
                              void* d_out, int out_size, void* d_ws, size_t ws_size,
                              hipStream_t stream)
{
    const float* u     = (const float*)d_in[0];
    const float* delta = (const float*)d_in[1];
    const float* Bm    = (const float*)d_in[2];
    const float* Cm    = (const float*)d_in[3];
    const float* A     = (const float*)d_in[4];
    const float* Dv    = (const float*)d_in[5];
    const float* dbias = (const float*)d_in[6];
    float* y = (float*)d_out;

    // workspace: sumdt [NCH*NCHAN] then S/x0 [NCH*NCHAN*NST]  (~13.4 MB total)
    float* sumdt = (float*)d_ws;
    float* S     = sumdt + (size_t)NCHAN * NCH;

    const dim3 grid(NCHAN / 256, NCH);
    ssm_phaseA<<<grid, 256, 0, stream>>>(u, delta, Bm, A, dbias, sumdt, S);
    ssm_phaseB<<<(NCHAN * NST) / 256, 256, 0, stream>>>(A, sumdt, S);
    ssm_phaseC<<<grid, 256, 0, stream>>>(u, delta, Bm, Cm, A, Dv, dbias, S, y);
}

// Round 3
// 493.971 us; speedup vs baseline: 1.4101x; 1.0032x over previous
//
#include <hip/hip_runtime.h>

#define BATCH 4
#define DIM   1536
#define SEQ   4096
#define NST   16
#define NCH   32      // chunks per sequence
#define CLEN  128     // chunk length: NCH*CLEN == SEQ
#define NCHAN (BATCH*DIM)
#define T     16      // subtile steps staged in LDS
#define LSTR  17      // padded LDS row stride (floats) -> <=2-way bank aliasing (free)
#define WLDS  (64*LSTR)   // per-wave u/d slice (floats)

#define LOG2E 1.4426950408889634f

// softplus matching jax.nn.softplus = log1p(exp(z)), overflow-safe
__device__ __forceinline__ float softplus_f(float z) {
    return (z > 20.f) ? z : __logf(1.f + __expf(z));
}
__device__ __forceinline__ float exp2_hw(float z) {
    return __builtin_amdgcn_exp2f(z);
}

// ---------------- Phase A: per-(channel,chunk) summaries ----------------
// S_n = sum_t (prod_{t'>t} a_{t'}) b_t  (local recurrence, x_in = 0)
// sumdt = sum_t dt_t   (chunk decay = exp2(A2_n*sumdt), A2 = A/ln2)
// S layout: [k][ch][n]
// Wave-private LDS staging, in-wave pipelined global loads, NO barriers.
__global__ __launch_bounds__(256, 4) void ssm_phaseA(
    const float* __restrict__ u, const float* __restrict__ delta,
    const float* __restrict__ Bm, const float* __restrict__ A,
    const float* __restrict__ dbias,
    float* __restrict__ sumdt_out, float* __restrict__ S_out)
{
    __shared__ float lu[4 * WLDS];
    __shared__ float ld[4 * WLDS];
    __shared__ float lB[4 * T * NST];

    const int tid = threadIdx.x;
    const int w   = tid >> 6;        // wave in block
    const int l   = tid & 63;        // lane
    const int ch  = blockIdx.x * 256 + tid;
    const int d   = ch % DIM;
    const int bb  = (blockIdx.x * 256) / DIM;   // uniform per block
    const int k   = blockIdx.y;
    const int s0  = k * CLEN;

    float* Lu = &lu[w * WLDS];
    float* Ld = &ld[w * WLDS];
    float* LB = &lB[w * T * NST];

    float A2[NST];
    const float* Ap = A + d * NST;
#pragma unroll
    for (int n = 0; n < NST; n++) A2[n] = Ap[n] * LOG2E;
    const float bias = dbias[d];

    // staging geometry: idx = q*64+l -> row co = q*16 + (l>>2), cols i4..i4+3
    const int coB = l >> 2;            // 0..15, add q*16
    const int i4  = (l & 3) << 2;      // 0,4,8,12
    const size_t rowbase = (size_t)(blockIdx.x * 256 + w * 64) * SEQ + s0;
    const size_t bbase   = (size_t)(bb * NST + coB) * SEQ + s0;  // B row n = coB

    float4 ru[4], rd[4], rb;
#pragma unroll
    for (int q = 0; q < 4; q++) {
        const size_t g = rowbase + (size_t)(q * 16 + coB) * SEQ + i4;
        ru[q] = *(const float4*)(u + g);
        rd[q] = *(const float4*)(delta + g);
    }
    rb = *(const float4*)(Bm + bbase + i4);

    float S[NST];
#pragma unroll
    for (int n = 0; n < NST; n++) S[n] = 0.f;
    float sumdt = 0.f;

    for (int ss = 0; ss < CLEN; ss += T) {
        // dump tile regs -> wave-private LDS (in-order DS pipe, no barrier)
#pragma unroll
        for (int q = 0; q < 4; q++) {
            float* pu = &Lu[(q * 16 + coB) * LSTR + i4];
            float* pd = &Ld[(q * 16 + coB) * LSTR + i4];
            pu[0] = ru[q].x; pu[1] = ru[q].y; pu[2] = ru[q].z; pu[3] = ru[q].w;
            pd[0] = rd[q].x; pd[1] = rd[q].y; pd[2] = rd[q].z; pd[3] = rd[q].w;
        }
        LB[(i4 + 0) * NST + coB] = rb.x;
        LB[(i4 + 1) * NST + coB] = rb.y;
        LB[(i4 + 2) * NST + coB] = rb.z;
        LB[(i4 + 3) * NST + coB] = rb.w;

        // prefetch next tile while computing this one
        if (ss + T < CLEN) {
#pragma unroll
            for (int q = 0; q < 4; q++) {
                const size_t g = rowbase + (size_t)(q * 16 + coB) * SEQ + (ss + T) + i4;
                ru[q] = *(const float4*)(u + g);
                rd[q] = *(const float4*)(delta + g);
            }
            rb = *(const float4*)(Bm + bbase + (ss + T) + i4);
        }

        const float* lur = &Lu[l * LSTR];
        const float* ldr = &Ld[l * LSTR];
#pragma unroll
        for (int i = 0; i < T; i++) {
            const float uu  = lur[i];
            const float dt  = softplus_f(ldr[i] + bias);
            const float dtu = dt * uu;
            sumdt += dt;
            const float* bi = &LB[i * NST];
#pragma unroll
            for (int n = 0; n < NST; n++) {
                const float a = exp2_hw(dt * A2[n]);
                S[n] = fmaf(a, S[n], dtu * bi[n]);
            }
        }
    }

    const size_t base = ((size_t)k * NCHAN + ch) * NST;   // [k][ch][n]
#pragma unroll
    for (int n = 0; n < NST; n += 4)
        *(float4*)(S_out + base + n) = make_float4(S[n], S[n+1], S[n+2], S[n+3]);
    sumdt_out[(size_t)k * NCHAN + ch] = sumdt;
}

// ---------------- Phase B: scan chunk summaries -> chunk entry states ----
// In-place on S[k][ch][n]: becomes x0 (state entering chunk k).
__global__ __launch_bounds__(256) void ssm_phaseB(
    const float* __restrict__ A, const float* __restrict__ sumdt,
    float* __restrict__ S)
{
    const int t  = blockIdx.x * 256 + threadIdx.x;
    const int n  = t & 15;
    const int ch = t >> 4;
    if (ch >= NCHAN) return;
    const int d = ch % DIM;
    const float An2 = A[d * NST + n] * LOG2E;
    float x = 0.f;
    for (int k = 0; k < NCH; k++) {
        const size_t idx = ((size_t)k * NCHAN + ch) * NST + n;
        const float s_old = S[idx];
        S[idx] = x;                                  // x0 for chunk k
        const float P = exp2_hw(An2 * sumdt[(size_t)k * NCHAN + ch]);
        x = fmaf(P, x, s_old);                       // state after chunk k
    }
}

// ---------------- Phase C: replay chunk from x0, emit y ------------------
// Same wave-private pipelined structure; y reuses the u LDS slice.
__global__ __launch_bounds__(256, 4) void ssm_phaseC(
    const float* __restrict__ u, const float* __restrict__ delta,
    const float* __restrict__ Bm, const float* __restrict__ Cm,
    const float* __restrict__ A, const float* __restrict__ Dv,
    const float* __restrict__ dbias, const float* __restrict__ x0,
    float* __restrict__ y)
{
    __shared__ float lu[4 * WLDS];
    __shared__ float ld[4 * WLDS];
    __shared__ float lB[4 * T * NST];
    __shared__ float lC[4 * T * NST];

    const int tid = threadIdx.x;
    const int w   = tid >> 6;
    const int l   = tid & 63;
    const int ch  = blockIdx.x * 256 + tid;
    const int d   = ch % DIM;
    const int bb  = (blockIdx.x * 256) / DIM;
    const int k   = blockIdx.y;
    const int s0  = k * CLEN;

    float* Lu = &lu[w * WLDS];
    float* Ld = &ld[w * WLDS];
    float* LB = &lB[w * T * NST];
    float* LC = &lC[w * T * NST];

    float A2[NST];
    const float* Ap = A + d * NST;
#pragma unroll
    for (int n = 0; n < NST; n++) A2[n] = Ap[n] * LOG2E;
    const float bias = dbias[d];
    const float Dval = Dv[d];

    float x[NST];
    const size_t xbase = ((size_t)k * NCHAN + ch) * NST;
#pragma unroll
    for (int n = 0; n < NST; n += 4) {
        const float4 xv = *(const float4*)(x0 + xbase + n);
        x[n] = xv.x; x[n+1] = xv.y; x[n+2] = xv.z; x[n+3] = xv.w;
    }

    const int coB = l >> 2;
    const int i4  = (l & 3) << 2;
    const size_t rowbase = (size_t)(blockIdx.x * 256 + w * 64) * SEQ + s0;
    const size_t bbase   = (size_t)(bb * NST + coB) * SEQ + s0;

    float4 ru[4], rd[4], rb, rc;
#pragma unroll
    for (int q = 0; q < 4; q++) {
        const size_t g = rowbase + (size_t)(q * 16 + coB) * SEQ + i4;
        ru[q] = *(const float4*)(u + g);
        rd[q] = *(const float4*)(delta + g);
    }
    rb = *(const float4*)(Bm + bbase + i4);
    rc = *(const float4*)(Cm + bbase + i4);

    for (int ss = 0; ss < CLEN; ss += T) {
#pragma unroll
        for (int q = 0; q < 4; q++) {
            float* pu = &Lu[(q * 16 + coB) * LSTR + i4];
            float* pd = &Ld[(q * 16 + coB) * LSTR + i4];
            pu[0] = ru[q].x; pu[1] = ru[q].y; pu[2] = ru[q].z; pu[3] = ru[q].w;
            pd[0] = rd[q].x; pd[1] = rd[q].y; pd[2] = rd[q].z; pd[3] = rd[q].w;
        }
        LB[(i4 + 0) * NST + coB] = rb.x;
        LB[(i4 + 1) * NST + coB] = rb.y;
        LB[(i4 + 2) * NST + coB] = rb.z;
        LB[(i4 + 3) * NST + coB] = rb.w;
        LC[(i4 + 0) * NST + coB] = rc.x;
        LC[(i4 + 1) * NST + coB] = rc.y;
        LC[(i4 + 2) * NST + coB] = rc.z;
        LC[(i4 + 3) * NST + coB] = rc.w;

        if (ss + T < CLEN) {
#pragma unroll
            for (int q = 0; q < 4; q++) {
                const size_t g = rowbase + (size_t)(q * 16 + coB) * SEQ + (ss + T) + i4;
                ru[q] = *(const float4*)(u + g);
                rd[q] = *(const float4*)(delta + g);
            }
            rb = *(const float4*)(Bm + bbase + (ss + T) + i4);
            rc = *(const float4*)(Cm + bbase + (ss + T) + i4);
        }

        float* lur = &Lu[l * LSTR];
        const float* ldr = &Ld[l * LSTR];
#pragma unroll
        for (int i = 0; i < T; i++) {
            const float uu  = lur[i];
            const float dt  = softplus_f(ldr[i] + bias);
            const float dtu = dt * uu;
            const float* bi = &LB[i * NST];
            const float* ci = &LC[i * NST];
            float acc = Dval * uu;
#pragma unroll
            for (int n = 0; n < NST; n++) {
                const float a = exp2_hw(dt * A2[n]);
                x[n] = fmaf(a, x[n], dtu * bi[n]);
                acc  = fmaf(x[n], ci[n], acc);
            }
            lur[i] = acc;   // overwrite u slot with y (read-then-write, same lane)
        }

        // coalesced y writeout (transposed read of the wave's slice)
#pragma unroll
        for (int q = 0; q < 4; q++) {
            const float* pr = &Lu[(q * 16 + coB) * LSTR + i4];
            *(float4*)(y + rowbase + (size_t)(q * 16 + coB) * SEQ + ss + i4) =
                make_float4(pr[0], pr[1], pr[2], pr[3]);
        }
    }
}

extern "C" void kernel_launch(void* const* d_in, const int* in_sizes, int n_in,
                              void* d_out, int out_size, void* d_ws, size_t ws_size,
                              hipStream_t stream)
{
    const float* u     = (const float*)d_in[0];
    const float* delta = (const float*)d_in[1];
    const float* Bm    = (const float*)d_in[2];
    const float* Cm    = (const float*)d_in[3];
    const float* A     = (const float*)d_in[4];
    const float* Dv    = (const float*)d_in[5];
    const float* dbias = (const float*)d_in[6];
    float* y = (float*)d_out;

    // workspace: sumdt [NCH*NCHAN] then S/x0 [NCH*NCHAN*NST]  (~13.4 MB total)
    float* sumdt = (float*)d_ws;
    float* S     = sumdt + (size_t)NCHAN * NCH;

    const dim3 grid(NCHAN / 256, NCH);
    ssm_phaseA<<<grid, 256, 0, stream>>>(u, delta, Bm, A, dbias, sumdt, S);
    ssm_phaseB<<<(NCHAN * NST) / 256, 256, 0, stream>>>(A, sumdt, S);
    ssm_phaseC<<<grid, 256, 0, stream>>>(u, delta, Bm, Cm, A, Dv, dbias, S, y);
}